// Round 5
// baseline (2138.360 us; speedup 1.0000x reference)
//
// Round 5: fp32 I/O (harness delivers fp16 refs as float32). Fused 4-bit dequant +
// FP16 MFMA GEMM, 128x128xBK32, f32 accum. out = f32( f16(acc) + f16(bias) ).
#include <hip/hip_runtime.h>
#include <stdint.h>

#define TOKENS 8192
#define KDIM   4096
#define NDIM   11008
#define BM 128
#define BN 128
#define BK 32

typedef _Float16 f16x8 __attribute__((ext_vector_type(8)));
typedef float    f32x4 __attribute__((ext_vector_type(4)));

__global__ __launch_bounds__(256, 2)
void wq_gemm(const float* __restrict__ X,  const int* __restrict__ Qw,
             const float* __restrict__ Sc, const float* __restrict__ Zp,
             const float* __restrict__ Bi, float* __restrict__ Out)
{
    __shared__ __align__(16) _Float16 As[BM * BK];   // [128 m][32 k], k contiguous
    __shared__ __align__(16) _Float16 Bs[BN * BK];   // [128 n][32 k], k contiguous

    const int t    = threadIdx.x;
    const int lane = t & 63;
    const int wid  = t >> 6;
    const int wr   = wid >> 1;                  // 2x2 wave grid; each wave: 64x64 out
    const int wc   = wid & 1;

    const int n0 = blockIdx.x * BN;
    const int m0 = blockIdx.y * BM;

    // ---- staging map: thread t -> tile row t>>1, k-half (t&1)*16 ----
    const int srow  = t >> 1;                   // 0..127
    const int shalf = (t & 1) << 4;             // 0 or 16 elements
    const float* xsrc = X  + (size_t)(m0 + srow) * KDIM + shalf;
    const int*   qsrc = Qw + (size_t)(n0 + srow) * KDIM + shalf;
    const float* scp  = Sc + n0 + srow;         // + g*NDIM per group
    const float* zpp  = Zp + n0 + srow;
    _Float16* adst = As + srow * BK + shalf;
    _Float16* bdst = Bs + srow * BK + shalf;

    // ---- fragment read map (16x16x32 f16: lane -> row lane&15, k=(lane>>4)*8..+7) ----
    const int fr = lane & 15;
    const int fq = lane >> 4;
    const _Float16* ard = As + (wr * 64 + fr) * BK + fq * 8;
    const _Float16* brd = Bs + (wc * 64 + fr) * BK + fq * 8;

    f32x4 acc[4][4];
#pragma unroll
    for (int i = 0; i < 4; ++i)
#pragma unroll
        for (int j = 0; j < 4; ++j)
            acc[i][j] = f32x4{0.f, 0.f, 0.f, 0.f};

    for (int kt = 0; kt < KDIM / BK; ++kt) {
        const int k0 = kt * BK;

        // A: 16 contiguous fp32 (64B) via 4x dwordx4; cvt to fp16 (exact: data is fp16-valued)
        const float4* xp = (const float4*)(xsrc + k0);
        const float4 x0 = xp[0], x1 = xp[1], x2 = xp[2], x3 = xp[3];
        const float xv[16] = {x0.x, x0.y, x0.z, x0.w, x1.x, x1.y, x1.z, x1.w,
                              x2.x, x2.y, x2.z, x2.w, x3.x, x3.y, x3.z, x3.w};
        f16x8 a0, a1;
#pragma unroll
        for (int j = 0; j < 8; ++j) {
            a0[j] = (_Float16)xv[j];
            a1[j] = (_Float16)xv[j + 8];
        }

        // B: 16 int32 q (64B), dequant f32, cvt fp16.
        // BK=32 tile lies inside one 128-wide group -> scalar scale/zero per thread.
        const int g = k0 >> 7;
        const float sf = scp[(size_t)g * NDIM];
        const float zf = zpp[(size_t)g * NDIM];
        const int4* qp = (const int4*)(qsrc + k0);
        const int4 q0 = qp[0], q1 = qp[1], q2 = qp[2], q3 = qp[3];
        const int qv[16] = {q0.x, q0.y, q0.z, q0.w, q1.x, q1.y, q1.z, q1.w,
                            q2.x, q2.y, q2.z, q2.w, q3.x, q3.y, q3.z, q3.w};
        f16x8 w0, w1;
#pragma unroll
        for (int j = 0; j < 8; ++j) {
            w0[j] = (_Float16)((float)qv[j]     * sf + zf);
            w1[j] = (_Float16)((float)qv[j + 8] * sf + zf);
        }

        // stage to LDS
        *(f16x8*)adst       = a0;
        *(f16x8*)(adst + 8) = a1;
        *(f16x8*)bdst       = w0;
        *(f16x8*)(bdst + 8) = w1;

        __syncthreads();

        f16x8 a[4], b[4];
#pragma unroll
        for (int i = 0; i < 4; ++i) a[i] = *(const f16x8*)(ard + i * 16 * BK);
#pragma unroll
        for (int j = 0; j < 4; ++j) b[j] = *(const f16x8*)(brd + j * 16 * BK);
#pragma unroll
        for (int i = 0; i < 4; ++i)
#pragma unroll
            for (int j = 0; j < 4; ++j)
                acc[i][j] = __builtin_amdgcn_mfma_f32_16x16x32_f16(a[i], b[j], acc[i][j], 0, 0, 0);

        __syncthreads();   // protect next iteration's LDS overwrite
    }

    // ---- epilogue: C/D map col=lane&15, row=(lane>>4)*4+reg; ref chain:
    // out = f32( f16(acc_f32) + f16(bias) )
#pragma unroll
    for (int j = 0; j < 4; ++j) {
        const int n = n0 + wc * 64 + j * 16 + fr;
        const _Float16 bv = (_Float16)Bi[n];
#pragma unroll
        for (int i = 0; i < 4; ++i) {
            const int mbase = m0 + wr * 64 + i * 16 + fq * 4;
#pragma unroll
            for (int r = 0; r < 4; ++r) {
                const _Float16 h = (_Float16)acc[i][j][r] + bv;
                Out[(size_t)(mbase + r) * NDIM + n] = (float)h;
            }
        }
    }
}

extern "C" void kernel_launch(void* const* d_in, const int* in_sizes, int n_in,
                              void* d_out, int out_size, void* d_ws, size_t ws_size,
                              hipStream_t stream) {
    // Bind by element count (robust): x 33554432, q 45088768, scales/szeros 352256
    // (dict order: scales first), bias 11008.
    const float* x  = nullptr;
    const int*   q  = nullptr;
    const float* sc = nullptr;
    const float* zp = nullptr;
    const float* bi = nullptr;
    for (int i = 0; i < n_in; ++i) {
        switch (in_sizes[i]) {
            case 33554432: x = (const float*)d_in[i]; break;
            case 45088768: q = (const int*)d_in[i]; break;
            case 352256:   if (!sc) sc = (const float*)d_in[i];
                           else     zp = (const float*)d_in[i];
                           break;
            case 11008:    bi = (const float*)d_in[i]; break;
            default: break;
        }
    }
    if (!x || !q || !sc || !zp || !bi) {   // fallback: dict order
        x  = (const float*)d_in[0];
        q  = (const int*)d_in[1];
        sc = (const float*)d_in[2];
        zp = (const float*)d_in[3];
        bi = (const float*)d_in[4];
    }
    float* out = (float*)d_out;

    dim3 grid(NDIM / BN, TOKENS / BM);  // (86, 64)
    wq_gemm<<<grid, dim3(256), 0, stream>>>(x, q, sc, zp, bi, out);
}

// Round 6
// 1066.053 us; speedup vs baseline: 2.0059x; 2.0059x over previous
//
// Round 6: two-pass — (1) pack q to 4-bit + x to fp16 in d_ws; (2) fused-dequant fp16
// MFMA GEMM, 128x128xBK64, padded LDS (stride 72 = odd*16B, conflict-free), XCD swizzle.
#include <hip/hip_runtime.h>
#include <stdint.h>

#define TOKENS 8192
#define KDIM   4096
#define NDIM   11008
#define BM 128
#define BN 128
#define BK 64
#define LDP 72                      // padded LDS row stride (elements)
#define QWPR 512                    // packed dwords per q row (4096/8)
#define PQ_BYTES (45088768u/8u*4u)  // 22544384
#define XH_BYTES (33554432ull*2ull) // 67108864
#define WS_NEED  (PQ_BYTES + XH_BYTES)

typedef _Float16 f16x8 __attribute__((ext_vector_type(8)));
typedef float    f32x4 __attribute__((ext_vector_type(4)));

// ---------------- pass 1a: pack 8 int32 (4-bit values) -> 1 dword ----------------
__global__ __launch_bounds__(256) void pack_q(const int* __restrict__ q,
                                              unsigned int* __restrict__ pq) {
    const unsigned int idx = blockIdx.x * 256 + threadIdx.x;   // 0..5636095
    const int4* p = (const int4*)(q + (size_t)idx * 8);
    const int4 a = p[0], b = p[1];
    unsigned int w = (unsigned int)(a.x & 15)
                   | ((unsigned int)(a.y & 15) << 4)
                   | ((unsigned int)(a.z & 15) << 8)
                   | ((unsigned int)(a.w & 15) << 12)
                   | ((unsigned int)(b.x & 15) << 16)
                   | ((unsigned int)(b.y & 15) << 20)
                   | ((unsigned int)(b.z & 15) << 24)
                   | ((unsigned int)(b.w & 15) << 28);
    pq[idx] = w;
}

// ---------------- pass 1b: x fp32 -> fp16 (exact: data is fp16-valued) ----------------
__global__ __launch_bounds__(256) void cvt_x(const float* __restrict__ x,
                                             _Float16* __restrict__ xh) {
    const size_t idx = (size_t)(blockIdx.x * 256 + threadIdx.x) * 8;
    const float4* p = (const float4*)(x + idx);
    const float4 a = p[0], b = p[1];
    f16x8 o;
    o[0] = (_Float16)a.x; o[1] = (_Float16)a.y; o[2] = (_Float16)a.z; o[3] = (_Float16)a.w;
    o[4] = (_Float16)b.x; o[5] = (_Float16)b.y; o[6] = (_Float16)b.z; o[7] = (_Float16)b.w;
    *(f16x8*)(xh + idx) = o;
}

// ---------------- pass 2: fused-dequant GEMM ----------------
__global__ __launch_bounds__(256, 2)
void wq_gemm_p(const _Float16* __restrict__ Xh, const unsigned int* __restrict__ Pq,
               const float* __restrict__ Sc, const float* __restrict__ Zp,
               const float* __restrict__ Bi, float* __restrict__ Out)
{
    __shared__ __align__(16) _Float16 As[BM * LDP];
    __shared__ __align__(16) _Float16 Bs[BN * LDP];

    const int t    = threadIdx.x;
    const int lane = t & 63;
    const int wid  = t >> 6;
    const int wr   = wid >> 1;                  // 2x2 waves; 64x64 out each
    const int wc   = wid & 1;

    // bijective XCD swizzle (5504 = 8 * 688), m fastest within an XCD chunk
    const unsigned int bid = blockIdx.x;
    const unsigned int wg  = (bid & 7u) * 688u + (bid >> 3);
    const int n0 = (int)(wg >> 6) * BN;         // 0..85
    const int m0 = (int)(wg & 63u) * BM;        // 0..63

    // ---- staging map: thread t -> tile row t>>1, k-half (t&1)*32 ----
    const int srow = t >> 1;                    // 0..127
    const int half = t & 1;                     // 32-element halves
    const _Float16*     xsrc = Xh + (size_t)(m0 + srow) * KDIM + half * 32;
    const unsigned int* qsrc = Pq + (size_t)(n0 + srow) * QWPR + half * 4;
    const float* scp = Sc + n0 + srow;          // + g*NDIM per group
    const float* zpp = Zp + n0 + srow;
    _Float16* adst = As + srow * LDP + half * 32;
    _Float16* bdst = Bs + srow * LDP + half * 32;

    // ---- fragment read map (16x16x32 f16: lane -> row lane&15, k=(lane>>4)*8..+7) ----
    const int fr = lane & 15;
    const int fq = lane >> 4;
    const _Float16* ard = As + (wr * 64 + fr) * LDP + fq * 8;
    const _Float16* brd = Bs + (wc * 64 + fr) * LDP + fq * 8;

    f32x4 acc[4][4];
#pragma unroll
    for (int i = 0; i < 4; ++i)
#pragma unroll
        for (int j = 0; j < 4; ++j)
            acc[i][j] = f32x4{0.f, 0.f, 0.f, 0.f};

    for (int kt = 0; kt < KDIM / BK; ++kt) {
        // A: 32 fp16 (64B) via 4x b128 loads
        const f16x8* xp = (const f16x8*)(xsrc + kt * BK);
        const f16x8 av0 = xp[0], av1 = xp[1], av2 = xp[2], av3 = xp[3];

        // B: 4 packed dwords = 32 nibbles; dequant f32 -> fp16.
        // BK=64 tile sits inside one 128-wide group -> scalar scale/zero.
        const int g = kt >> 1;
        const float sf = scp[(size_t)g * NDIM];
        const float zf = zpp[(size_t)g * NDIM];
        const uint4 pw = *(const uint4*)(qsrc + kt * 8);
        f16x8 w[4];
        const unsigned int pv[4] = {pw.x, pw.y, pw.z, pw.w};
#pragma unroll
        for (int d = 0; d < 4; ++d)
#pragma unroll
            for (int j = 0; j < 8; ++j)
                w[d][j] = (_Float16)((float)((pv[d] >> (4 * j)) & 15u) * sf + zf);

        // stage to LDS
        ((f16x8*)adst)[0] = av0; ((f16x8*)adst)[1] = av1;
        ((f16x8*)adst)[2] = av2; ((f16x8*)adst)[3] = av3;
        ((f16x8*)bdst)[0] = w[0]; ((f16x8*)bdst)[1] = w[1];
        ((f16x8*)bdst)[2] = w[2]; ((f16x8*)bdst)[3] = w[3];

        __syncthreads();

#pragma unroll
        for (int kk = 0; kk < 2; ++kk) {
            f16x8 a[4], b[4];
#pragma unroll
            for (int i = 0; i < 4; ++i) a[i] = *(const f16x8*)(ard + i * 16 * LDP + kk * 32);
#pragma unroll
            for (int j = 0; j < 4; ++j) b[j] = *(const f16x8*)(brd + j * 16 * LDP + kk * 32);
#pragma unroll
            for (int i = 0; i < 4; ++i)
#pragma unroll
                for (int j = 0; j < 4; ++j)
                    acc[i][j] = __builtin_amdgcn_mfma_f32_16x16x32_f16(a[i], b[j], acc[i][j], 0, 0, 0);
        }

        __syncthreads();
    }

    // ---- epilogue: C/D map col=lane&15, row=(lane>>4)*4+reg; out = f32(f16(acc)+f16(bias))
#pragma unroll
    for (int j = 0; j < 4; ++j) {
        const int n = n0 + wc * 64 + j * 16 + fr;
        const _Float16 bv = (_Float16)Bi[n];
#pragma unroll
        for (int i = 0; i < 4; ++i) {
            const int mbase = m0 + wr * 64 + i * 16 + fq * 4;
#pragma unroll
            for (int r = 0; r < 4; ++r) {
                const _Float16 h = (_Float16)acc[i][j][r] + bv;
                Out[(size_t)(mbase + r) * NDIM + n] = (float)h;
            }
        }
    }
}

// ---------------- fallback: round-5 direct kernel (no workspace) ----------------
__global__ __launch_bounds__(256, 2)
void wq_gemm_direct(const float* __restrict__ X,  const int* __restrict__ Qw,
                    const float* __restrict__ Sc, const float* __restrict__ Zp,
                    const float* __restrict__ Bi, float* __restrict__ Out)
{
    __shared__ __align__(16) _Float16 As[BM * 32];
    __shared__ __align__(16) _Float16 Bs[BN * 32];
    const int t = threadIdx.x, lane = t & 63, wid = t >> 6;
    const int wr = wid >> 1, wc = wid & 1;
    const int n0 = blockIdx.x * BN, m0 = blockIdx.y * BM;
    const int srow = t >> 1, shalf = (t & 1) << 4;
    const float* xsrc = X + (size_t)(m0 + srow) * KDIM + shalf;
    const int*   qsrc = Qw + (size_t)(n0 + srow) * KDIM + shalf;
    const float* scp = Sc + n0 + srow;
    const float* zpp = Zp + n0 + srow;
    _Float16* adst = As + srow * 32 + shalf;
    _Float16* bdst = Bs + srow * 32 + shalf;
    const int fr = lane & 15, fq = lane >> 4;
    const _Float16* ard = As + (wr * 64 + fr) * 32 + fq * 8;
    const _Float16* brd = Bs + (wc * 64 + fr) * 32 + fq * 8;
    f32x4 acc[4][4];
#pragma unroll
    for (int i = 0; i < 4; ++i)
#pragma unroll
        for (int j = 0; j < 4; ++j) acc[i][j] = f32x4{0.f, 0.f, 0.f, 0.f};
    for (int kt = 0; kt < KDIM / 32; ++kt) {
        const int k0 = kt * 32;
        const float4* xp = (const float4*)(xsrc + k0);
        const float4 x0 = xp[0], x1 = xp[1], x2 = xp[2], x3 = xp[3];
        const float xv[16] = {x0.x, x0.y, x0.z, x0.w, x1.x, x1.y, x1.z, x1.w,
                              x2.x, x2.y, x2.z, x2.w, x3.x, x3.y, x3.z, x3.w};
        f16x8 a0, a1;
#pragma unroll
        for (int j = 0; j < 8; ++j) { a0[j] = (_Float16)xv[j]; a1[j] = (_Float16)xv[j + 8]; }
        const int g = k0 >> 7;
        const float sf = scp[(size_t)g * NDIM];
        const float zf = zpp[(size_t)g * NDIM];
        const int4* qp = (const int4*)(qsrc + k0);
        const int4 q0 = qp[0], q1 = qp[1], q2 = qp[2], q3 = qp[3];
        const int qv[16] = {q0.x, q0.y, q0.z, q0.w, q1.x, q1.y, q1.z, q1.w,
                            q2.x, q2.y, q2.z, q2.w, q3.x, q3.y, q3.z, q3.w};
        f16x8 w0, w1;
#pragma unroll
        for (int j = 0; j < 8; ++j) {
            w0[j] = (_Float16)((float)qv[j]     * sf + zf);
            w1[j] = (_Float16)((float)qv[j + 8] * sf + zf);
        }
        *(f16x8*)adst = a0; *(f16x8*)(adst + 8) = a1;
        *(f16x8*)bdst = w0; *(f16x8*)(bdst + 8) = w1;
        __syncthreads();
        f16x8 a[4], b[4];
#pragma unroll
        for (int i = 0; i < 4; ++i) a[i] = *(const f16x8*)(ard + i * 16 * 32);
#pragma unroll
        for (int j = 0; j < 4; ++j) b[j] = *(const f16x8*)(brd + j * 16 * 32);
#pragma unroll
        for (int i = 0; i < 4; ++i)
#pragma unroll
            for (int j = 0; j < 4; ++j)
                acc[i][j] = __builtin_amdgcn_mfma_f32_16x16x32_f16(a[i], b[j], acc[i][j], 0, 0, 0);
        __syncthreads();
    }
#pragma unroll
    for (int j = 0; j < 4; ++j) {
        const int n = n0 + wc * 64 + j * 16 + fr;
        const _Float16 bv = (_Float16)Bi[n];
#pragma unroll
        for (int i = 0; i < 4; ++i) {
            const int mbase = m0 + wr * 64 + i * 16 + fq * 4;
#pragma unroll
            for (int r = 0; r < 4; ++r) {
                const _Float16 h = (_Float16)acc[i][j][r] + bv;
                Out[(size_t)(mbase + r) * NDIM + n] = (float)h;
            }
        }
    }
}

extern "C" void kernel_launch(void* const* d_in, const int* in_sizes, int n_in,
                              void* d_out, int out_size, void* d_ws, size_t ws_size,
                              hipStream_t stream) {
    const float* x  = nullptr;
    const int*   q  = nullptr;
    const float* sc = nullptr;
    const float* zp = nullptr;
    const float* bi = nullptr;
    for (int i = 0; i < n_in; ++i) {
        switch (in_sizes[i]) {
            case 33554432: x = (const float*)d_in[i]; break;
            case 45088768: q = (const int*)d_in[i]; break;
            case 352256:   if (!sc) sc = (const float*)d_in[i];
                           else     zp = (const float*)d_in[i];
                           break;
            case 11008:    bi = (const float*)d_in[i]; break;
            default: break;
        }
    }
    if (!x || !q || !sc || !zp || !bi) {
        x  = (const float*)d_in[0];
        q  = (const int*)d_in[1];
        sc = (const float*)d_in[2];
        zp = (const float*)d_in[3];
        bi = (const float*)d_in[4];
    }
    float* out = (float*)d_out;

    if (ws_size >= (size_t)WS_NEED) {
        unsigned int* pq = (unsigned int*)d_ws;
        _Float16*     xh = (_Float16*)((char*)d_ws + PQ_BYTES);
        pack_q<<<5636096 / 256, 256, 0, stream>>>(q, pq);
        cvt_x<<<33554432 / 8 / 256, 256, 0, stream>>>(x, xh);
        wq_gemm_p<<<(NDIM / BN) * (TOKENS / BM), 256, 0, stream>>>(xh, pq, sc, zp, bi, out);
    } else {
        dim3 grid(NDIM / BN, TOKENS / BM);
        wq_gemm_direct<<<grid, dim3(256), 0, stream>>>(x, q, sc, zp, bi, out);
    }
}